// Round 11
// baseline (813.015 us; speedup 1.0000x reference)
//
#include <hip/hip_runtime.h>
#include <stdint.h>

#define TPB 1024
#define NJ 8           // float4 chunks per thread: 1024*8*4 = 32768 = H
#define HSZ 32768
#define NW (TPB / 64)  // 16 waves
#define CAP 2048       // candidate capacity (threshold bin ~300 for N(0,1))

// LDS-only barrier: orders LDS but leaves global loads (prefetch) in flight.
#define BARRIER() do { \
    asm volatile("s_waitcnt lgkmcnt(0)" ::: "memory"); \
    __builtin_amdgcn_s_barrier(); \
} while (0)

// order-preserving float->uint key: bigger float => bigger key
__device__ __forceinline__ uint32_t f2k(float f) {
    uint32_t u = __float_as_uint(f);
    return u ^ (0x80000000u | (uint32_t)(-(int32_t)(u >> 31)));
}

struct Sm {
    uint32_t hist[4096];        // 16 KB: L1 bins (bits[31:20]) then L2 (bits[19:8])
    uint32_t h256[256];         // 1 KB: L3 bins (bits[7:0])
    uint32_t cand_key[CAP];     // 8 KB
    uint32_t cand_col[CAP];     // 8 KB
    uint32_t wtot[NW];
    uint32_t bin, rem, eqcnt, ncand, chunk_base;
};                              // ~33 KB

// Suffix-select over hist[4096] (descending bins = larger values).
// Finds bin B with count(>B) < need <= count(>=B); bin=B, rem=need-count(>B).
__device__ __forceinline__ void select4096(Sm& sm, uint32_t need, int t) {
    const int lane = t & 63, wid = t >> 6;
    uint32_t b[4], pt = 0;
#pragma unroll
    for (int jj = 0; jj < 4; ++jj) { b[jj] = sm.hist[t * 4 + jj]; pt += b[jj]; }
    uint32_t pre = pt;  // wave suffix-inclusive scan
#pragma unroll
    for (int off = 1; off < 64; off <<= 1) {
        uint32_t n = (uint32_t)__shfl_down((int)pre, off, 64);
        if (lane + off < 64) pre += n;
    }
    if (lane == 0) sm.wtot[wid] = pre;
    BARRIER();
    uint32_t wsuf = 0;
    for (int w = wid + 1; w < NW; ++w) wsuf += sm.wtot[w];
    const uint32_t Sincl = pre + wsuf;
    const uint32_t Sexcl = Sincl - pt;
    if (Sexcl < need && Sincl >= need) {
        uint32_t run = Sexcl;
#pragma unroll
        for (int jj = 3; jj >= 0; --jj) {
            if (run + b[jj] >= need) { sm.bin = (uint32_t)(t * 4 + jj); sm.rem = need - run; break; }
            run += b[jj];
        }
    }
    BARRIER();
}

// Same over h256; also reports count of the selected bin.
__device__ __forceinline__ void select256(Sm& sm, uint32_t need, int t) {
    const int lane = t & 63, wid = t >> 6;
    uint32_t pt = (t < 256) ? sm.h256[t] : 0u;
    uint32_t pre = pt;
#pragma unroll
    for (int off = 1; off < 64; off <<= 1) {
        uint32_t n = (uint32_t)__shfl_down((int)pre, off, 64);
        if (lane + off < 64) pre += n;
    }
    if (lane == 0) sm.wtot[wid] = pre;
    BARRIER();
    uint32_t wsuf = 0;
    for (int w = wid + 1; w < NW; ++w) wsuf += sm.wtot[w];
    const uint32_t Sincl = pre + wsuf;
    const uint32_t Sexcl = Sincl - pt;
    if (t < 256 && Sexcl < need && Sincl >= need) {
        sm.bin = (uint32_t)t; sm.rem = need - Sexcl; sm.eqcnt = pt;
    }
    BARRIER();
}

__global__ __launch_bounds__(TPB) void topk_scatter_kernel(
    const float* __restrict__ x,
    const int* __restrict__ kp,
    float* __restrict__ out,
    int nrows)
{
    __shared__ Sm sm;
    const int t = threadIdx.x;
    const int gs = (int)gridDim.x;
    const int ki = kp[0];

    if (ki <= 0 || ki >= HSZ) {  // degenerate: all zeros or identity copy
        for (int r = (int)blockIdx.x; r < nrows; r += gs) {
            const float4* xr4 = reinterpret_cast<const float4*>(x + (size_t)r * HSZ);
            float4* o4 = reinterpret_cast<float4*>(out + (size_t)r * HSZ);
#pragma unroll
            for (int j = 0; j < NJ; ++j) {
                float4 o;
                if (ki <= 0) { o.x = o.y = o.z = o.w = 0.0f; }
                else o = xr4[j * TPB + t];
                o4[j * TPB + t] = o;
            }
        }
        return;
    }
    const uint32_t k = (uint32_t)ki;

    int r = (int)blockIdx.x;
    if (r >= nrows) return;

    // prologue: issue first row's loads; zero hists
    float4 vv[NJ];
    {
        const float4* xr4 = reinterpret_cast<const float4*>(x + (size_t)r * HSZ);
#pragma unroll
        for (int j = 0; j < NJ; ++j) vv[j] = xr4[j * TPB + t];
    }
#pragma unroll
    for (int i = 0; i < 4; ++i) sm.hist[i * TPB + t] = 0u;
    if (t < 256) sm.h256[t] = 0u;
    BARRIER();

    for (;;) {
        const int rn = r + gs;
        const bool hasnext = (rn < nrows);
        const float4* xr4 = reinterpret_cast<const float4*>(x + (size_t)r * HSZ);
        const float4* xn4 = hasnext ? reinterpret_cast<const float4*>(x + (size_t)rn * HSZ) : nullptr;
        float4* out4 = reinterpret_cast<float4*>(out + (size_t)r * HSZ);
        float* outr = out + (size_t)r * HSZ;

        // ===== phase A: L1 histogram (bits[31:20]) fused with load arrival =====
#pragma unroll
        for (int j = 0; j < NJ; ++j) {
            atomicAdd(&sm.hist[f2k(vv[j].x) >> 20], 1u);
            atomicAdd(&sm.hist[f2k(vv[j].y) >> 20], 1u);
            atomicAdd(&sm.hist[f2k(vv[j].z) >> 20], 1u);
            atomicAdd(&sm.hist[f2k(vv[j].w) >> 20], 1u);
        }
        if (t == 0) sm.ncand = 0u;
        BARRIER();
        select4096(sm, k, t);
        const uint32_t B1 = sm.bin;
        const uint32_t need2 = sm.rem;

        // ===== compact + finalize non-threshold words + prefetch next row =====
        // zero hist for L2 reuse (sel1 already consumed it)
#pragma unroll
        for (int i = 0; i < 4; ++i) sm.hist[i * TPB + t] = 0u;
        uint32_t dmask = 0;   // float4s containing a bin-B1 element (deferred)
#pragma unroll
        for (int j = 0; j < NJ; ++j) {
            float4 v = vv[j];
            float vals[4] = { v.x, v.y, v.z, v.w };
            uint32_t keys[4];
            bool any = false;
#pragma unroll
            for (int e = 0; e < 4; ++e) { keys[e] = f2k(vals[e]); any |= ((keys[e] >> 20) == B1); }
            if (!any) {
                float4 o;
                o.x = ((keys[0] >> 20) > B1) ? vals[0] : 0.0f;
                o.y = ((keys[1] >> 20) > B1) ? vals[1] : 0.0f;
                o.z = ((keys[2] >> 20) > B1) ? vals[2] : 0.0f;
                o.w = ((keys[3] >> 20) > B1) ? vals[3] : 0.0f;
                out4[j * TPB + t] = o;          // FINAL store (only store to these)
            } else {
                dmask |= (1u << j);
#pragma unroll
                for (int e = 0; e < 4; ++e) {
                    if ((keys[e] >> 20) == B1) {
                        uint32_t pos = atomicAdd(&sm.ncand, 1u);
                        if (pos < CAP) {
                            sm.cand_key[pos] = keys[e];
                            sm.cand_col[pos] = (uint32_t)((j * TPB + t) * 4 + e);
                        }
                    }
                }
            }
            if (hasnext) vv[j] = xn4[j * TPB + t];   // prefetch: vv[j] dead here
        }
        BARRIER();   // cand + hist zeros visible
        const uint32_t C = sm.ncand;

        if (C <= CAP) {
            // ===== refine L2 (bits[19:8]) then L3 (bits[7:0]) over candidates =====
            for (uint32_t i = t; i < C; i += TPB)
                atomicAdd(&sm.hist[(sm.cand_key[i] >> 8) & 0xFFFu], 1u);
            BARRIER();
            select4096(sm, need2, t);
            const uint32_t pref = (B1 << 12) | sm.bin;
            const uint32_t need3 = sm.rem;
            for (uint32_t i = t; i < C; i += TPB) {
                uint32_t key = sm.cand_key[i];
                if ((key >> 8) == pref) atomicAdd(&sm.h256[key & 0xFFu], 1u);
            }
            BARRIER();
            select256(sm, need3, t);
            const uint32_t K = (pref << 8) | sm.bin;
            const uint32_t eqneed = sm.rem;
            const bool simple = (sm.eqcnt == eqneed);

            // ===== deferred stores: re-read own threshold words (L2-hot) =====
            if (dmask) {
#pragma unroll
                for (int j = 0; j < NJ; ++j) {
                    if ((dmask >> j) & 1u) {
                        float4 v = xr4[j * TPB + t];
                        float vals[4] = { v.x, v.y, v.z, v.w };
                        float ov[4];
#pragma unroll
                        for (int e = 0; e < 4; ++e) {
                            uint32_t key = f2k(vals[e]);
                            bool take = key > K;
                            if (key == K) {
                                if (simple) take = true;
                                else {   // exact tie-break: lowest columns win
                                    uint32_t col = (uint32_t)((j * TPB + t) * 4 + e);
                                    uint32_t rank = 0;
                                    for (uint32_t m = 0; m < C; ++m)
                                        if (sm.cand_key[m] == K && sm.cand_col[m] < col) ++rank;
                                    take = (rank < eqneed);
                                }
                            }
                            ov[e] = take ? vals[e] : 0.0f;
                        }
                        float4 o; o.x = ov[0]; o.y = ov[1]; o.z = ov[2]; o.w = ov[3];
                        out4[j * TPB + t] = o;   // only store to these words
                    }
                }
            }
            // zero hists for next row (L2/L3 dirty)
#pragma unroll
            for (int i = 0; i < 4; ++i) sm.hist[i * TPB + t] = 0u;
            if (t < 256) sm.h256[t] = 0u;
            BARRIER();
        } else {
            // ===== overflow fallback (C > CAP; ~never for Gaussian) =====
            // vv holds NEXT row already; re-read current row from global (L2-hot).
            for (int j = 0; j < NJ; ++j) {
                float4 v = xr4[j * TPB + t];
                float vals[4] = { v.x, v.y, v.z, v.w };
#pragma unroll
                for (int e = 0; e < 4; ++e) {
                    uint32_t key = f2k(vals[e]);
                    if ((key >> 20) == B1) atomicAdd(&sm.hist[(key >> 8) & 0xFFFu], 1u);
                }
            }
            BARRIER();
            select4096(sm, need2, t);
            const uint32_t pref = (B1 << 12) | sm.bin;
            const uint32_t need3 = sm.rem;
            for (int j = 0; j < NJ; ++j) {
                float4 v = xr4[j * TPB + t];
                float vals[4] = { v.x, v.y, v.z, v.w };
#pragma unroll
                for (int e = 0; e < 4; ++e) {
                    uint32_t key = f2k(vals[e]);
                    if ((key >> 8) == pref) atomicAdd(&sm.h256[key & 0xFFu], 1u);
                }
            }
            BARRIER();
            select256(sm, need3, t);
            const uint32_t K = (pref << 8) | sm.bin;
            const uint32_t eqneed = sm.rem;
            const uint32_t eqcnt = sm.eqcnt;

            if (eqcnt == eqneed) {
                // full idempotent rewrite (same thread owns same addresses)
                for (int j = 0; j < NJ; ++j) {
                    float4 v = xr4[j * TPB + t];
                    float4 o;
                    o.x = (f2k(v.x) >= K) ? v.x : 0.0f;
                    o.y = (f2k(v.y) >= K) ? v.y : 0.0f;
                    o.z = (f2k(v.z) >= K) ? v.z : 0.0f;
                    o.w = (f2k(v.w) >= K) ? v.w : 0.0f;
                    out4[j * TPB + t] = o;
                }
            } else {
                // ordered selection among ==K by lowest column, chunk-by-chunk
                if (t == 0) sm.chunk_base = 0u;
                BARRIER();
                const int lane = t & 63;
                const int wid = t >> 6;
                for (int j = 0; j < NJ; ++j) {
                    float4 v = xr4[j * TPB + t];
                    float vals[4] = { v.x, v.y, v.z, v.w };
                    uint32_t keys[4];
                    uint32_t e0 = 0;
#pragma unroll
                    for (int e = 0; e < 4; ++e) { keys[e] = f2k(vals[e]); e0 += (keys[e] == K) ? 1u : 0u; }
                    uint32_t pre = e0;
                    for (int off = 1; off < 64; off <<= 1) {
                        uint32_t n = (uint32_t)__shfl_up((int)pre, off, 64);
                        if (lane >= off) pre += n;
                    }
                    if (lane == 63) sm.wtot[wid] = pre;
                    BARRIER();
                    uint32_t before = sm.chunk_base + (pre - e0);
                    for (int w = 0; w < wid; ++w) before += sm.wtot[w];
                    float ov[4];
#pragma unroll
                    for (int e = 0; e < 4; ++e) {
                        bool take = keys[e] > K;
                        if (keys[e] == K) { take = (before < eqneed); ++before; }
                        ov[e] = take ? vals[e] : 0.0f;
                    }
                    float4 o; o.x = ov[0]; o.y = ov[1]; o.z = ov[2]; o.w = ov[3];
                    out4[j * TPB + t] = o;
                    BARRIER();
                    if (t == 0) {
                        uint32_t s2 = sm.chunk_base;
#pragma unroll
                        for (int w = 0; w < NW; ++w) s2 += sm.wtot[w];
                        sm.chunk_base = s2;
                    }
                    BARRIER();
                }
            }
            // zero hists for next row
#pragma unroll
            for (int i = 0; i < 4; ++i) sm.hist[i * TPB + t] = 0u;
            if (t < 256) sm.h256[t] = 0u;
            BARRIER();
        }

        if (!hasnext) break;
        r = rn;
    }
}

extern "C" void kernel_launch(void* const* d_in, const int* in_sizes, int n_in,
                              void* d_out, int out_size, void* d_ws, size_t ws_size,
                              hipStream_t stream) {
    const float* x = (const float*)d_in[0];
    const int* kp = (const int*)d_in[1];
    float* out = (float*)d_out;
    const int total = in_sizes[0];
    const int rows = total / HSZ;        // 8192
    int grid = rows < 256 ? rows : 256;  // persistent: 1 block per CU
    topk_scatter_kernel<<<grid, TPB, 0, stream>>>(x, kp, out, rows);
}